// Round 3
// baseline (941.709 us; speedup 1.0000x reference)
//
#include <hip/hip_runtime.h>
#include <stdint.h>

typedef __bf16   bf16x8 __attribute__((ext_vector_type(8)));
typedef float    f32x4  __attribute__((ext_vector_type(4)));
typedef uint32_t u32x4  __attribute__((ext_vector_type(4)));
typedef uint32_t u32x2  __attribute__((ext_vector_type(2)));
typedef unsigned short u16x8 __attribute__((ext_vector_type(8)));

#define L_SEQ 8192
#define DIM   768
#define DROW  8768     // dupG row length in dwords (zero-padded tail)
// dupG[d][i] = ( k[8223-i] in lo16, k[8222-i] in hi16 ), scaled by 1/16384.
// k[s]=0 for s<0 or s>8191  ->  dupG zero for i<31 and i>=8224.

// Workspace layout (bytes):
//   dupG u32  [768][8768]    @ 0            size 26,935,296
//   uT   bf16 [768][8][8192] @ 26,935,296   size 100,663,296
//   yT   bf16 [768][8][8192] @ 127,598,592  size 100,663,296

// ---------------- zero the dupG pad regions (re-poisoned every call) ------
__global__ __launch_bounds__(256) void pad_kernel(uint32_t* __restrict__ dupG)
{
  int d = blockIdx.x;
  const int NPAD = 31 + (DROW - 8224);
  for (int j = threadIdx.x; j < NPAD; j += 256) {
    int i = (j < 31) ? j : 8224 + (j - 31);
    dupG[(size_t)d * DROW + i] = 0u;
  }
}

// ---------------- filter MLP -> dupG pairs --------------------------------
__global__ __launch_bounds__(256) void filter_kernel(
    const float* __restrict__ w_in, const float* __restrict__ b_in,
    const float* __restrict__ freq_in,
    const float* __restrict__ w_h0, const float* __restrict__ b_h0,
    const float* __restrict__ freq_h0,
    const float* __restrict__ w_h1, const float* __restrict__ b_h1,
    const float* __restrict__ freq_h1,
    const float* __restrict__ w_out,
    uint32_t* __restrict__ dupG)
{
  __shared__ float h1[33][65];
  __shared__ float h2[33][65];
  __shared__ unsigned short kv[33][64];
  __shared__ float wch[64][64];           // staged weight chunk [r][n]

  const int c = blockIdx.x;               // 0..255
  const int sbase = c << 5;
  const int tid = threadIdx.x;

  for (int p = tid; p < 33 * 64; p += 256) {
    int j = p >> 6, n = p & 63;
    int s = sbase - 1 + j;
    float t  = s * (1.0f / 8191.0f);
    float ph = s * (float)(6.283185307179586 * 1e-4 / 8192.0);
    float a = t * w_in[n] + cosf(ph) * w_in[64 + n] + (-sinf(ph)) * w_in[128 + n] + b_in[n];
    h1[j][n] = sinf(freq_in[n] * a);
  }
  // stage w_h0
  for (int p = tid; p < 64 * 64; p += 256) wch[p >> 6][p & 63] = w_h0[p];
  __syncthreads();
  for (int p = tid; p < 33 * 64; p += 256) {
    int j = p >> 6, n = p & 63;
    float a = b_h0[n];
    for (int r = 0; r < 64; ++r) a += h1[j][r] * wch[r][n];
    h2[j][n] = sinf(freq_h0[n] * a);
  }
  __syncthreads();
  // stage w_h1
  for (int p = tid; p < 64 * 64; p += 256) wch[p >> 6][p & 63] = w_h1[p];
  __syncthreads();
  for (int p = tid; p < 33 * 64; p += 256) {
    int j = p >> 6, n = p & 63;
    float a = b_h1[n];
    for (int r = 0; r < 64; ++r) a += h2[j][r] * wch[r][n];
    h1[j][n] = sinf(freq_h1[n] * a);      // h1 <- h3
  }
  __syncthreads();

  for (int dc = 0; dc < 12; ++dc) {
    for (int p = tid; p < 64 * 64; p += 256) {
      int r = p >> 6, dd = p & 63;
      wch[r][dd] = w_out[r * DIM + dc * 64 + dd];
    }
    __syncthreads();
    for (int p = tid; p < 33 * 64; p += 256) {
      int j = p >> 6, dd = p & 63;
      float a = 0.0f;
      for (int r = 0; r < 64; ++r) a += h1[j][r] * wch[r][dd];
      int s = sbase - 1 + j;
      int d = dc * 64 + dd;
      float delta = fabsf(-3.070113457f - 12.280453827f * (d * (1.0f / 767.0f)));
      float t = s * (1.0f / 8191.0f);
      float val = (s < 0) ? 0.0f : a * expf(-t * delta) * 6.103515625e-05f;
      kv[j][dd] = __builtin_bit_cast(unsigned short, (__bf16)val);
    }
    __syncthreads();
    for (int p = tid; p < 32 * 64; p += 256) {
      int j = p >> 6, dd = p & 63;
      int d = dc * 64 + dd;
      int i = 8223 - (sbase + j);
      dupG[(size_t)d * DROW + i] =
          (uint32_t)kv[j + 1][dd] | ((uint32_t)kv[j][dd] << 16);
    }
    if (c == 255 && tid < 64) {
      int d = dc * 64 + tid;
      dupG[(size_t)d * DROW + 31] = ((uint32_t)kv[32][tid] << 16);
    }
    __syncthreads();
  }
}

// ---------------- x (B,L,D) fp32 -> uT[d][b][t] bf16 (vectorized) ---------
// tile[t][d], row stride 68 ushorts. Phase1: float4 loads, 8B LDS writes.
// Phase2: 8-scalar LDS gather per lane -> 16B global store.
__global__ __launch_bounds__(256) void transpose_in_kernel(
    const float* __restrict__ x, unsigned short* __restrict__ uT)
{
  __shared__ unsigned short tile[64][68];
  int b = blockIdx.z;
  int t0 = blockIdx.y * 64;
  int d0 = blockIdx.x * 64;
  int tid = threadIdx.x;

  int ld = tid & 15;            // d-quad index
  int tq = tid >> 4;            // 0..15
#pragma unroll
  for (int it = 0; it < 4; ++it) {
    int trow = tq + 16 * it;
    f32x4 xv = *(const f32x4*)&x[((size_t)b * L_SEQ + t0 + trow) * DIM + d0 + 4 * ld];
    unsigned short s0 = __builtin_bit_cast(unsigned short, (__bf16)xv[0]);
    unsigned short s1 = __builtin_bit_cast(unsigned short, (__bf16)xv[1]);
    unsigned short s2 = __builtin_bit_cast(unsigned short, (__bf16)xv[2]);
    unsigned short s3 = __builtin_bit_cast(unsigned short, (__bf16)xv[3]);
    u32x2 pk = { (uint32_t)s0 | ((uint32_t)s1 << 16),
                 (uint32_t)s2 | ((uint32_t)s3 << 16) };
    *(u32x2*)&tile[trow][4 * ld] = pk;
  }
  __syncthreads();

  int l = tid & 63, w = tid >> 6;
  int toct = l & 7;
#pragma unroll
  for (int it = 0; it < 2; ++it) {
    int d = 8 * w + 32 * it + (l >> 3);
    u16x8 o;
#pragma unroll
    for (int c2 = 0; c2 < 8; ++c2) o[c2] = tile[8 * toct + c2][d];
    *(u16x8*)&uT[((size_t)(d0 + d) * 8 + b) * L_SEQ + t0 + 8 * toct] = o;
  }
}

// ---------------- conv: yT[d][b][t] = sum_tau u[b][tau] k[t-tau] ----------
// t-span 1024/block; packed-M (batch, t+16 half); 8 merged tiles/wave.
// Pipelining: A-fragments pa[8] prefetched one GROUP (8 bodies) ahead via
// per-body reload-after-use; dG chunk staged one group ahead (dwordx4).
#define LOADFRAG(dst, absdw) {                                    \
    int _p = ((absdw) & 2047);                                    \
    u32x4 _u = { buf[_p], buf[_p + 2], buf[_p + 4], buf[_p + 6] };\
    dst = __builtin_bit_cast(bf16x8, _u); }

__global__ __launch_bounds__(256) void conv_kernel(
    const uint32_t* __restrict__ dupG,
    const unsigned short* __restrict__ uT,
    unsigned short* __restrict__ yT)
{
  const int d   = blockIdx.y;
  const int T0  = blockIdx.x << 10;      // t-span 1024
  const int tid = threadIdx.x;
  const int lane = tid & 63;
  const int w    = tid >> 6;
  const int m = lane & 15, q = lane >> 4;
  const int h = (lane >> 3) & 1;
  __shared__ uint32_t buf[2080];         // 2048 circular + 32 mirror

  f32x4 acc[8] = {};
  bf16x8 fr2[8];
  bf16x8 pa[8];
  bf16x8 zfr = {};

  float delta = fabsf(-3.070113457f - 12.280453827f * (d * (1.0f / 767.0f)));
  int S = (int)(8191.0f * 3.5065578f / delta);   // decay < 0.03 cutoff
  int tau_start = T0 - S;
  tau_start = (tau_start < 0) ? 0 : (tau_start & ~31);
  int niter = ((T0 + 992 - tau_start) >> 5) + 1;
  niter = (niter + 7) & ~7;              // pad with zero-contribution iters

  const uint32_t* dG = dupG + (size_t)d * DROW;
  const unsigned short* uTd = uT + ((size_t)d << 16);

  int i0 = 7200 + tau_start - T0;        // window base (dword idx), >= 32

  // A base: tau = tau_start - 16 + 16h + 8q; row stride 16 KiB.
  int a_off = ((lane & 7) << 14) + ((tau_start - 16 + (h << 4) + (q << 3)) << 1);

  // issue group-0 A-fragment loads first (latency overlaps LDS prefill)
#pragma unroll
  for (int rr = 0; rr < 8; ++rr)
    pa[rr] = *(const bf16x8*)((const char*)uTd + a_off + (rr << 6));

  // prefill window [i0, i0+1280): covers all reads of group 0
  for (int j4 = tid * 4; j4 < 1280; j4 += 1024) {
    int i = i0 + j4;                     // i0 mult of 32 -> 16B aligned
    u32x4 v = *(const u32x4*)&dG[i];
    int pos = i & 2047;
    *(u32x4*)&buf[pos] = v;
    if (pos < 32) *(u32x4*)&buf[2048 + pos] = v;
  }
  __syncthreads();

  const bool kill = (tau_start == 0) & (h == 0) & (q < 2);  // tau<0 taps
  if (kill) pa[0] = zfr;

  int vb = i0 + 1007 - (w << 8) - m + (q << 3);   // abs dword, body 0, tile 0
  int chunk_i = i0 + 1280;

  // prologue: B fragments for tiles j=1..7 of body 0
  LOADFRAG(fr2[7], vb - 32);
  LOADFRAG(fr2[6], vb - 64);
  LOADFRAG(fr2[5], vb - 96);
  LOADFRAG(fr2[4], vb - 128);
  LOADFRAG(fr2[3], vb - 160);
  LOADFRAG(fr2[2], vb - 192);
  LOADFRAG(fr2[1], vb - 224);

#define MFMA_J(rr, j)                                                          \
  acc[j] = __builtin_amdgcn_mfma_f32_16x16x32_bf16(                            \
      afrag, fr2[((rr) - (j)) & 7], acc[j], 0, 0, 0);

// consume pa[rr]; immediately re-issue its load for NEXT group (8-body
// issue-to-use distance hides HBM latency). afrag copy lets the load issue
// before the MFMAs (register rename), MFMAs read the copied value.
#define BODY(rr) {                                                             \
    LOADFRAG(fr2[(rr) & 7], vb + ((rr) << 5));                                 \
    bf16x8 afrag = pa[rr];                                                     \
    pa[rr] = *(const bf16x8*)((const char*)uTd + a_off + ((rr) << 6) + 512);   \
    MFMA_J(rr, 1) MFMA_J(rr, 2) MFMA_J(rr, 3) MFMA_J(rr, 4)                    \
    MFMA_J(rr, 5) MFMA_J(rr, 6) MFMA_J(rr, 7) MFMA_J(rr, 0)                    \
  }

  for (int nn = 0; nn < niter; nn += 8) {
    u32x4 stage = {};
    int si4 = chunk_i + (tid << 2);
    if (tid < 64) {
      int iv = (si4 < 8740) ? si4 : 8740;  // clamp into zero tail
      stage = *(const u32x4*)&dG[iv];
    }
    BODY(0) BODY(1) BODY(2) BODY(3)
    BODY(4) BODY(5) BODY(6) BODY(7)
    if (tid < 64) {
      int pos = si4 & 2047;
      *(u32x4*)&buf[pos] = stage;
      if (pos < 32) *(u32x4*)&buf[2048 + pos] = stage;
    }
    __syncthreads();
    a_off += 512; vb += 256; chunk_i += 256;
  }

  // C[row][col]: col = m = t-offset(16), row = q*4+r = (b, h):
  //   y[b][T0 + 256w + 32j + 16h + m]
#pragma unroll
  for (int j = 0; j < 8; ++j) {
    int tb_ = T0 + (w << 8) + (j << 5) + m;
#pragma unroll
    for (int r = 0; r < 4; ++r) {
      int row = q * 4 + r;
      int bb = row & 7;
      int hh = row >> 3;
      yT[((size_t)(d * 8 + bb) << 13) + tb_ + (hh << 4)] =
          __builtin_bit_cast(unsigned short, (__bf16)acc[j][r]);
    }
  }
}

// ---------------- yT[d][b][t] bf16 -> out (B,L,D) fp32 + bias (vector) ----
__global__ __launch_bounds__(256) void transpose_out_kernel(
    const unsigned short* __restrict__ yT, const float* __restrict__ bias,
    float* __restrict__ out)
{
  __shared__ unsigned short tile[64][68];
  int b = blockIdx.z;
  int t0 = blockIdx.y * 64;
  int d0 = blockIdx.x * 64;
  int tid = threadIdx.x;

  int l = tid & 63, w = tid >> 6;
  int toct = l & 7;
#pragma unroll
  for (int it = 0; it < 2; ++it) {
    int d = 8 * w + 32 * it + (l >> 3);
    u16x8 o = *(const u16x8*)&yT[((size_t)(d0 + d) * 8 + b) * L_SEQ + t0 + 8 * toct];
#pragma unroll
    for (int c2 = 0; c2 < 8; ++c2) tile[8 * toct + c2][d] = o[c2];
  }
  __syncthreads();

  int ld = tid & 15;
  int tq = tid >> 4;
  f32x4 bs = *(const f32x4*)&bias[d0 + 4 * ld];
#pragma unroll
  for (int it = 0; it < 4; ++it) {
    int trow = tq + 16 * it;
    u32x2 pk = *(const u32x2*)&tile[trow][4 * ld];
    f32x4 ov;
    ov[0] = (float)__builtin_bit_cast(__bf16, (unsigned short)(pk[0] & 0xffff)) + bs[0];
    ov[1] = (float)__builtin_bit_cast(__bf16, (unsigned short)(pk[0] >> 16))    + bs[1];
    ov[2] = (float)__builtin_bit_cast(__bf16, (unsigned short)(pk[1] & 0xffff)) + bs[2];
    ov[3] = (float)__builtin_bit_cast(__bf16, (unsigned short)(pk[1] >> 16))    + bs[3];
    *(f32x4*)&out[((size_t)b * L_SEQ + t0 + trow) * DIM + d0 + 4 * ld] = ov;
  }
}

extern "C" void kernel_launch(void* const* d_in, const int* in_sizes, int n_in,
                              void* d_out, int out_size, void* d_ws, size_t ws_size,
                              hipStream_t stream)
{
  const float* x       = (const float*)d_in[0];
  const float* w_in    = (const float*)d_in[1];
  const float* b_in    = (const float*)d_in[2];
  const float* freq_in = (const float*)d_in[3];
  const float* w_h0    = (const float*)d_in[4];
  const float* b_h0    = (const float*)d_in[5];
  const float* freq_h0 = (const float*)d_in[6];
  const float* w_h1    = (const float*)d_in[7];
  const float* b_h1    = (const float*)d_in[8];
  const float* freq_h1 = (const float*)d_in[9];
  const float* w_out   = (const float*)d_in[10];
  const float* bias    = (const float*)d_in[11];

  char* ws = (char*)d_ws;
  uint32_t* dupG = (uint32_t*)(ws);
  unsigned short* uT = (unsigned short*)(ws + 26935296);
  unsigned short* yT = (unsigned short*)(ws + 127598592);
  float* out = (float*)d_out;

  hipLaunchKernelGGL(pad_kernel, dim3(DIM), dim3(256), 0, stream, dupG);
  hipLaunchKernelGGL(filter_kernel, dim3(256), dim3(256), 0, stream,
                     w_in, b_in, freq_in, w_h0, b_h0, freq_h0,
                     w_h1, b_h1, freq_h1, w_out, dupG);
  hipLaunchKernelGGL(transpose_in_kernel, dim3(12, 128, 8), dim3(256), 0, stream, x, uT);
  hipLaunchKernelGGL(conv_kernel, dim3(8, DIM), dim3(256), 0, stream, dupG, uT, yT);
  hipLaunchKernelGGL(transpose_out_kernel, dim3(12, 128, 8), dim3(256), 0, stream,
                     yT, bias, out);
}

// Round 4
// 760.825 us; speedup vs baseline: 1.2377x; 1.2377x over previous
//
#include <hip/hip_runtime.h>
#include <stdint.h>

typedef __bf16   bf16x8 __attribute__((ext_vector_type(8)));
typedef float    f32x4  __attribute__((ext_vector_type(4)));
typedef uint32_t u32x4  __attribute__((ext_vector_type(4)));
typedef uint32_t u32x2  __attribute__((ext_vector_type(2)));
typedef unsigned short u16x8 __attribute__((ext_vector_type(8)));

#define L_SEQ 8192
#define DIM   768
#define DROW  8768     // dupG row length in dwords (zero-padded tail)
// dupG[d][i] = ( k[8223-i] in lo16, k[8222-i] in hi16 ), scaled by 1/16384.
// k[s]=0 for s<0 or s>8191  ->  dupG zero for i<31 and i>=8224.

// Workspace layout (bytes):
//   dupG u32  [768][8768]    @ 0            size 26,935,296
//   uT   bf16 [768][8][8192] @ 26,935,296   size 100,663,296
//   yT   bf16 [768][8][8192] @ 127,598,592  size 100,663,296

// ---------------- zero the dupG pad regions (re-poisoned every call) ------
__global__ __launch_bounds__(256) void pad_kernel(uint32_t* __restrict__ dupG)
{
  int d = blockIdx.x;
  const int NPAD = 31 + (DROW - 8224);
  for (int j = threadIdx.x; j < NPAD; j += 256) {
    int i = (j < 31) ? j : 8224 + (j - 31);
    dupG[(size_t)d * DROW + i] = 0u;
  }
}

// ---------------- filter MLP -> dupG pairs --------------------------------
// grid (256, 4): blockIdx.x = s-chunk, blockIdx.y = dc-group (3 chunks each).
// MLP layers recomputed per dc-group (cheap) to quadruple occupancy.
__global__ __launch_bounds__(256) void filter_kernel(
    const float* __restrict__ w_in, const float* __restrict__ b_in,
    const float* __restrict__ freq_in,
    const float* __restrict__ w_h0, const float* __restrict__ b_h0,
    const float* __restrict__ freq_h0,
    const float* __restrict__ w_h1, const float* __restrict__ b_h1,
    const float* __restrict__ freq_h1,
    const float* __restrict__ w_out,
    uint32_t* __restrict__ dupG)
{
  __shared__ float h1[33][65];
  __shared__ float h2[33][65];
  __shared__ unsigned short kv[33][64];
  __shared__ float wch[64][64];

  const int c = blockIdx.x;               // 0..255
  const int dcg = blockIdx.y;             // 0..3
  const int sbase = c << 5;
  const int tid = threadIdx.x;

  for (int p = tid; p < 33 * 64; p += 256) {
    int j = p >> 6, n = p & 63;
    int s = sbase - 1 + j;
    float t  = s * (1.0f / 8191.0f);
    float ph = s * (float)(6.283185307179586 * 1e-4 / 8192.0);
    float a = t * w_in[n] + cosf(ph) * w_in[64 + n] + (-sinf(ph)) * w_in[128 + n] + b_in[n];
    h1[j][n] = sinf(freq_in[n] * a);
  }
  for (int p = tid; p < 64 * 64; p += 256) wch[p >> 6][p & 63] = w_h0[p];
  __syncthreads();
  for (int p = tid; p < 33 * 64; p += 256) {
    int j = p >> 6, n = p & 63;
    float a = b_h0[n];
    for (int r = 0; r < 64; ++r) a += h1[j][r] * wch[r][n];
    h2[j][n] = sinf(freq_h0[n] * a);
  }
  __syncthreads();
  for (int p = tid; p < 64 * 64; p += 256) wch[p >> 6][p & 63] = w_h1[p];
  __syncthreads();
  for (int p = tid; p < 33 * 64; p += 256) {
    int j = p >> 6, n = p & 63;
    float a = b_h1[n];
    for (int r = 0; r < 64; ++r) a += h2[j][r] * wch[r][n];
    h1[j][n] = sinf(freq_h1[n] * a);      // h1 <- h3
  }
  __syncthreads();

  for (int dc = dcg * 3; dc < dcg * 3 + 3; ++dc) {
    for (int p = tid; p < 64 * 64; p += 256) {
      int r = p >> 6, dd = p & 63;
      wch[r][dd] = w_out[r * DIM + dc * 64 + dd];
    }
    __syncthreads();
    for (int p = tid; p < 33 * 64; p += 256) {
      int j = p >> 6, dd = p & 63;
      float a = 0.0f;
      for (int r = 0; r < 64; ++r) a += h1[j][r] * wch[r][dd];
      int s = sbase - 1 + j;
      int d = dc * 64 + dd;
      float delta = fabsf(-3.070113457f - 12.280453827f * (d * (1.0f / 767.0f)));
      float t = s * (1.0f / 8191.0f);
      float val = (s < 0) ? 0.0f : a * expf(-t * delta) * 6.103515625e-05f;
      kv[j][dd] = __builtin_bit_cast(unsigned short, (__bf16)val);
    }
    __syncthreads();
    for (int p = tid; p < 32 * 64; p += 256) {
      int j = p >> 6, dd = p & 63;
      int d = dc * 64 + dd;
      int i = 8223 - (sbase + j);
      dupG[(size_t)d * DROW + i] =
          (uint32_t)kv[j + 1][dd] | ((uint32_t)kv[j][dd] << 16);
    }
    if (c == 255 && tid < 64) {
      int d = dc * 64 + tid;
      dupG[(size_t)d * DROW + 31] = ((uint32_t)kv[32][tid] << 16);
    }
    __syncthreads();
  }
}

// ---------------- x (B,L,D) fp32 -> uT[d][b][t] bf16 (vectorized) ---------
__global__ __launch_bounds__(256) void transpose_in_kernel(
    const float* __restrict__ x, unsigned short* __restrict__ uT)
{
  __shared__ unsigned short tile[64][68];
  int b = blockIdx.z;
  int t0 = blockIdx.y * 64;
  int d0 = blockIdx.x * 64;
  int tid = threadIdx.x;

  int ld = tid & 15;
  int tq = tid >> 4;
#pragma unroll
  for (int it = 0; it < 4; ++it) {
    int trow = tq + 16 * it;
    f32x4 xv = *(const f32x4*)&x[((size_t)b * L_SEQ + t0 + trow) * DIM + d0 + 4 * ld];
    unsigned short s0 = __builtin_bit_cast(unsigned short, (__bf16)xv[0]);
    unsigned short s1 = __builtin_bit_cast(unsigned short, (__bf16)xv[1]);
    unsigned short s2 = __builtin_bit_cast(unsigned short, (__bf16)xv[2]);
    unsigned short s3 = __builtin_bit_cast(unsigned short, (__bf16)xv[3]);
    u32x2 pk = { (uint32_t)s0 | ((uint32_t)s1 << 16),
                 (uint32_t)s2 | ((uint32_t)s3 << 16) };
    *(u32x2*)&tile[trow][4 * ld] = pk;
  }
  __syncthreads();

  int l = tid & 63, w = tid >> 6;
  int toct = l & 7;
#pragma unroll
  for (int it = 0; it < 2; ++it) {
    int d = 8 * w + 32 * it + (l >> 3);
    u16x8 o;
#pragma unroll
    for (int c2 = 0; c2 < 8; ++c2) o[c2] = tile[8 * toct + c2][d];
    *(u16x8*)&uT[((size_t)(d0 + d) * 8 + b) * L_SEQ + t0 + 8 * toct] = o;
  }
}

// ---------------- conv: yT[d][b][t] = sum_tau u[b][tau] k[t-tau] ----------
// t-span 1024/block; packed-M (batch, t+16 half); 8 merged tiles/wave.
// A (u) staged into LDS via global_load_lds, double-buffered per 8-body
// group; afrag = conflict-free ds_read_b128, register-prefetched 1 body
// ahead. dG (B) staged one group ahead via registers. One barrier/group;
// all DMA issued at group top -> barrier's vmcnt(0) drain is free.
#define LOADFRAG(dst, absdw) {                                    \
    int _p = ((absdw) & 2047);                                    \
    u32x4 _u = { buf[_p], buf[_p + 2], buf[_p + 4], buf[_p + 6] };\
    dst = __builtin_bit_cast(bf16x8, _u); }

// A tile: per group, taus [W0+256g-16, W0+256g+256) = 272 taus x 8 rows,
// row-contiguous: slot s(16B) -> b = s/34, elem8 = s%34.
// LDS byte for (b, elem e) = 544*b + 2*e.
#define DSREAD_A(rr, P) (*(const bf16x8*)((P) + abyte + ((rr) << 6)))

typedef __attribute__((address_space(1))) const void g_void;
typedef __attribute__((address_space(3))) void lds_void;

__global__ __launch_bounds__(256) void conv_kernel(
    const uint32_t* __restrict__ dupG,
    const unsigned short* __restrict__ uT,
    unsigned short* __restrict__ yT)
{
  const int d   = blockIdx.y;
  const int T0  = blockIdx.x << 10;      // t-span 1024
  const int tid = threadIdx.x;
  const int lane = tid & 63;
  const int w    = tid >> 6;
  const int m = lane & 15, q = lane >> 4;
  const int h = (lane >> 3) & 1;
  __shared__ uint32_t buf[2080];         // 2048 circular + 32 mirror (dG)
  __shared__ __align__(16) char As0[5120];  // A tile dbuf (320 slots each;
  __shared__ __align__(16) char As1[5120];  // slots 272..319 = DMA slack)

  f32x4 acc[8] = {};
  bf16x8 fr2[8];
  bf16x8 zfr = {};

  float delta = fabsf(-3.070113457f - 12.280453827f * (d * (1.0f / 767.0f)));
  int S = (int)(8191.0f * 3.5065578f / delta);   // decay < 0.03 cutoff
  int tau_start = T0 - S;
  tau_start = (tau_start < 0) ? 0 : (tau_start & ~31);
  int niter = ((T0 + 992 - tau_start) >> 5) + 1;
  niter = (niter + 7) & ~7;              // pad with zero-contribution iters

  const uint32_t* dG = dupG + (size_t)d * DROW;
  const unsigned short* uTd = uT + ((size_t)d << 16);

  int i0 = 7200 + tau_start - T0;        // dG window base (dword idx), >= 32

  // ---- A staging source addresses (per thread slot) ----
  // instr0: slot s0 = tid (all waves); instr1: slot s1 = 256+lane (wave 0).
  int s0 = tid;
  int b0 = s0 / 34, r0 = s0 - 34 * b0;
  const char* ga0 = (const char*)uTd + b0 * 16384 + (tau_start - 16 + r0 * 8) * 2;
  int s1 = 256 + lane;
  int b1 = s1 / 34, r1 = s1 - 34 * b1;
  const char* ga1 = (const char*)uTd + b1 * 16384 + (tau_start - 16 + r1 * 8) * 2;

  const char* Acur = As0;
  const char* Anxt = As1;

  // issue group-0 A stage into As0 (latency overlaps dG prefill)
  __builtin_amdgcn_global_load_lds((g_void*)ga0, (lds_void*)(As0 + (w << 10)), 16, 0, 0);
  if (w == 0)
    __builtin_amdgcn_global_load_lds((g_void*)ga1, (lds_void*)(As0 + 4096), 16, 0, 0);
  ga0 += 512; ga1 += 512;

  // prefill dG window [i0, i0+1280): covers all reads of group 0
  for (int j4 = tid * 4; j4 < 1280; j4 += 1024) {
    int i = i0 + j4;                     // i0 mult of 32 -> 16B aligned
    u32x4 v = *(const u32x4*)&dG[i];
    int pos = i & 2047;
    *(u32x4*)&buf[pos] = v;
    if (pos < 32) *(u32x4*)&buf[2048 + pos] = v;
  }
  __syncthreads();                       // drains A0 DMA + prefill

  // per-lane A read base: byte = 544*b + 32*h + 16*q
  const int abyte = 544 * (lane & 7) + (h << 5) + (q << 4);

  int vb = i0 + 1007 - (w << 8) - m + (q << 3);   // abs dword, body 0, tile 0
  int chunk_i = i0 + 1280;

  // prologue: B fragments for tiles j=1..7 of body 0
  LOADFRAG(fr2[7], vb - 32);
  LOADFRAG(fr2[6], vb - 64);
  LOADFRAG(fr2[5], vb - 96);
  LOADFRAG(fr2[4], vb - 128);
  LOADFRAG(fr2[3], vb - 160);
  LOADFRAG(fr2[2], vb - 192);
  LOADFRAG(fr2[1], vb - 224);

  // body-0 afrag + tau<0 kill (global body 0 only)
  bf16x8 pa_c = DSREAD_A(0, Acur);
  if ((tau_start == 0) & (h == 0) & (q < 2)) pa_c = zfr;

#define MFMA_J(rr, j)                                                          \
  acc[j] = __builtin_amdgcn_mfma_f32_16x16x32_bf16(                            \
      afrag, fr2[((rr) - (j)) & 7], acc[j], 0, 0, 0);

#define BODYP(rr) {                                                            \
    LOADFRAG(fr2[(rr) & 7], vb + ((rr) << 5));                                 \
    bf16x8 afrag = pa_c;                                                       \
    pa_c = DSREAD_A((rr) + 1, Acur);                                           \
    MFMA_J(rr, 1) MFMA_J(rr, 2) MFMA_J(rr, 3) MFMA_J(rr, 4)                    \
    MFMA_J(rr, 5) MFMA_J(rr, 6) MFMA_J(rr, 7) MFMA_J(rr, 0)                    \
  }
#define BODYL(rr) {                                                            \
    LOADFRAG(fr2[(rr) & 7], vb + ((rr) << 5));                                 \
    bf16x8 afrag = pa_c;                                                       \
    MFMA_J(rr, 1) MFMA_J(rr, 2) MFMA_J(rr, 3) MFMA_J(rr, 4)                    \
    MFMA_J(rr, 5) MFMA_J(rr, 6) MFMA_J(rr, 7) MFMA_J(rr, 0)                    \
  }

  for (int nn = 0; nn < niter; nn += 8) {
    // issue next group's A stage into Anxt (drained free at the barrier)
    __builtin_amdgcn_global_load_lds((g_void*)ga0, (lds_void*)(Anxt + (w << 10)), 16, 0, 0);
    if (w == 0)
      __builtin_amdgcn_global_load_lds((g_void*)ga1, (lds_void*)(Anxt + 4096), 16, 0, 0);
    ga0 += 512; ga1 += 512;
    // stage next group's dG chunk into registers
    u32x4 stage = {};
    int si4 = chunk_i + (tid << 2);
    if (tid < 64) {
      int iv = (si4 < 8740) ? si4 : 8740;  // clamp into zero tail
      stage = *(const u32x4*)&dG[iv];
    }
    BODYP(0) BODYP(1) BODYP(2) BODYP(3)
    BODYP(4) BODYP(5) BODYP(6) BODYL(7)
    if (tid < 64) {
      int pos = si4 & 2047;
      *(u32x4*)&buf[pos] = stage;
      if (pos < 32) *(u32x4*)&buf[2048 + pos] = stage;
    }
    __syncthreads();
    { const char* t_ = Acur; Acur = Anxt; Anxt = t_; }
    vb += 256; chunk_i += 256;
    pa_c = DSREAD_A(0, Acur);            // body 0 of next group
  }

  // C[row][col]: col = m = t-offset(16), row = q*4+r = (b, h):
  //   y[b][T0 + 256w + 32j + 16h + m]
#pragma unroll
  for (int j = 0; j < 8; ++j) {
    int tb_ = T0 + (w << 8) + (j << 5) + m;
#pragma unroll
    for (int r = 0; r < 4; ++r) {
      int row = q * 4 + r;
      int bb = row & 7;
      int hh = row >> 3;
      yT[((size_t)(d * 8 + bb) << 13) + tb_ + (hh << 4)] =
          __builtin_bit_cast(unsigned short, (__bf16)acc[j][r]);
    }
  }
}

// ---------------- yT[d][b][t] bf16 -> out (B,L,D) fp32 + bias (vector) ----
__global__ __launch_bounds__(256) void transpose_out_kernel(
    const unsigned short* __restrict__ yT, const float* __restrict__ bias,
    float* __restrict__ out)
{
  __shared__ unsigned short tile[64][68];
  int b = blockIdx.z;
  int t0 = blockIdx.y * 64;
  int d0 = blockIdx.x * 64;
  int tid = threadIdx.x;

  int l = tid & 63, w = tid >> 6;
  int toct = l & 7;
#pragma unroll
  for (int it = 0; it < 2; ++it) {
    int d = 8 * w + 32 * it + (l >> 3);
    u16x8 o = *(const u16x8*)&yT[((size_t)(d0 + d) * 8 + b) * L_SEQ + t0 + 8 * toct];
#pragma unroll
    for (int c2 = 0; c2 < 8; ++c2) tile[8 * toct + c2][d] = o[c2];
  }
  __syncthreads();

  int ld = tid & 15;
  int tq = tid >> 4;
  f32x4 bs = *(const f32x4*)&bias[d0 + 4 * ld];
#pragma unroll
  for (int it = 0; it < 4; ++it) {
    int trow = tq + 16 * it;
    u32x2 pk = *(const u32x2*)&tile[trow][4 * ld];
    f32x4 ov;
    ov[0] = (float)__builtin_bit_cast(__bf16, (unsigned short)(pk[0] & 0xffff)) + bs[0];
    ov[1] = (float)__builtin_bit_cast(__bf16, (unsigned short)(pk[0] >> 16))    + bs[1];
    ov[2] = (float)__builtin_bit_cast(__bf16, (unsigned short)(pk[1] & 0xffff)) + bs[2];
    ov[3] = (float)__builtin_bit_cast(__bf16, (unsigned short)(pk[1] >> 16))    + bs[3];
    *(f32x4*)&out[((size_t)b * L_SEQ + t0 + trow) * DIM + d0 + 4 * ld] = ov;
  }
}

extern "C" void kernel_launch(void* const* d_in, const int* in_sizes, int n_in,
                              void* d_out, int out_size, void* d_ws, size_t ws_size,
                              hipStream_t stream)
{
  const float* x       = (const float*)d_in[0];
  const float* w_in    = (const float*)d_in[1];
  const float* b_in    = (const float*)d_in[2];
  const float* freq_in = (const float*)d_in[3];
  const float* w_h0    = (const float*)d_in[4];
  const float* b_h0    = (const float*)d_in[5];
  const float* freq_h0 = (const float*)d_in[6];
  const float* w_h1    = (const float*)d_in[7];
  const float* b_h1    = (const float*)d_in[8];
  const float* freq_h1 = (const float*)d_in[9];
  const float* w_out   = (const float*)d_in[10];
  const float* bias    = (const float*)d_in[11];

  char* ws = (char*)d_ws;
  uint32_t* dupG = (uint32_t*)(ws);
  unsigned short* uT = (unsigned short*)(ws + 26935296);
  unsigned short* yT = (unsigned short*)(ws + 127598592);
  float* out = (float*)d_out;

  hipLaunchKernelGGL(pad_kernel, dim3(DIM), dim3(256), 0, stream, dupG);
  hipLaunchKernelGGL(filter_kernel, dim3(256, 4), dim3(256), 0, stream,
                     w_in, b_in, freq_in, w_h0, b_h0, freq_h0,
                     w_h1, b_h1, freq_h1, w_out, dupG);
  hipLaunchKernelGGL(transpose_in_kernel, dim3(12, 128, 8), dim3(256), 0, stream, x, uT);
  hipLaunchKernelGGL(conv_kernel, dim3(8, DIM), dim3(256), 0, stream, dupG, uT, yT);
  hipLaunchKernelGGL(transpose_out_kernel, dim3(12, 128, 8), dim3(256), 0, stream,
                     yT, bias, out);
}